// Round 1
// 380.561 us; speedup vs baseline: 1.0040x; 1.0040x over previous
//
#include <hip/hip_runtime.h>

// TransposeTDLayer: y[b,p,o] = bias[p,o] + sum_{j in [j0,j1)} X[b,l_j,:] . W[k_j,l_j,o,:]
// l_j = p/2 - j, k_j = (p&1) + 2j.
// Grid: 2060 blocks = (p, o-half). Each block: 64(b) x 64(o) output tile.
// bf16 MFMA, fp32 accumulate. W (268 MB) is single-use -> nontemporal loads so it
// doesn't evict the hot 17 MB X working set from L2/L3. Out is write-once ->
// nontemporal stores. Conversion fp32->bf16 = add 0x8000 (round-half-up) + v_perm pack.
//
// R3 (this round): kernel is HBM-BW-bound on the W stream (floor ~49us; deduced
// actual ~58us; dur_us also contains 2x ~162us harness poison fills). Two tail
// levers: (1) LPT block order -- full 4-j items first, 24 short edge-p items last;
// (2) X loads issued before W loads and X staged first, so sA staging waits only
// vmcnt(8) (X, L2-fast) while the 8 W loads keep streaming (vmcnt(0) only at sB).

#define B_   64
#define L_   512
#define CI_  128
#define CO_  128
#define P_   1030

typedef __attribute__((ext_vector_type(8))) short v8s;
typedef __attribute__((ext_vector_type(4))) float v4f;   // native vector: OK for nontemporal builtins

// pack two fp32 -> two bf16 (a in low half), round-half-up: 2 adds + 1 v_perm
__device__ inline unsigned pack_bf16(float a, float b) {
  unsigned ua = __float_as_uint(a) + 0x8000u;
  unsigned ub = __float_as_uint(b) + 0x8000u;
  // D.byte[0,1] = ua.byte[2,3] (S1), D.byte[2,3] = ub.byte[2,3] (S0)
  return __builtin_amdgcn_perm(ub, ua, 0x07060302u);
}

// Fragment-linear LDS chunk index with XOR swizzle (verified R1/R2).
// Chunk (rt, ks, q, rm) holds rows r = rt*16+rm, k-elems i = ks*32 + q*8 .. +8.
__device__ inline int chunk_idx(int rt, int ks, int q, int rm) {
  return (rt * 4 + ks) * 64 + q * 16 + (rm ^ (ks * 4 + q));
}

__global__ __launch_bounds__(256, 4)
void tdconv_mfma_kernel(const float* __restrict__ x, const float* __restrict__ w,
                        const float* __restrict__ bias, float* __restrict__ out) {
  __shared__ __align__(16) unsigned short sA[64 * 128];  // X tile bf16, 16 KB
  __shared__ __align__(16) unsigned short sB[64 * 128];  // W half-tile bf16, 16 KB

  const int bid  = blockIdx.x;
  // LPT remap: items 0..2035 -> interior p in [6,1023] (full 4-j blocks),
  // items 2036..2059 -> edge p in {0..5} u {1024..1029} (1-3 j, shortest last).
  int p;
  if (bid < 2036) {
    p = 6 + (bid >> 1);
  } else {
    const int e = (bid - 2036) >> 1;
    p = (e < 6) ? e : (1018 + e);
  }
  const int oh   = bid & 1;       // Cout half
  const int t    = threadIdx.x;
  const int lane = t & 63;
  const int wid  = t >> 6;
  const int wb   = wid >> 1;      // b-half (32 rows each)
  const int wq   = wid & 1;       // o-quarter within the half (32 each)
  const int q    = lane >> 4;
  const int rm   = lane & 15;

  const int lmax = p >> 1;
  const int j0 = lmax > (L_ - 1) ? lmax - (L_ - 1) : 0;
  const int j1 = (lmax + 1) < 4 ? (lmax + 1) : 4;

  const float4* X4 = (const float4*)x;
  const v4f*   W4 = (const v4f*)w;

  v4f acc[2][2];
#pragma unroll
  for (int a = 0; a < 2; ++a)
#pragma unroll
    for (int b = 0; b < 2; ++b) acc[a][b] = (v4f)0.0f;

  float4 xv[8];   // X stage: 64x128 fp32 = 2048 float4 / 256 thr
  v4f    wv[8];   // W half stage: 64x128 fp32 = 2048 float4 / 256 thr

  // prologue: loads for first valid j (X first, then W -> partial waits later)
  {
    const int l = lmax - j0;
    const int k = (p & 1) + 2 * j0;
    const int xbase = l * 32;                                // float4 units
    const int wbase = (k * L_ + l) * 4096 + oh * 2048;       // contiguous 32KB
#pragma unroll
    for (int it = 0; it < 8; ++it) {
      const int idx = it * 256 + t;
      xv[it] = X4[((idx >> 5) << 14) + xbase + (idx & 31)];
    }
#pragma unroll
    for (int it = 0; it < 8; ++it) {
      const int idx = it * 256 + t;
      wv[it] = __builtin_nontemporal_load(&W4[wbase + idx]);
    }
  }

  for (int jj = j0; jj < j1; ++jj) {
    __syncthreads();  // previous iter's LDS reads complete

    // Stage X first: only the 8 X loads (issued oldest) must have landed, so the
    // compiler can wait vmcnt(8) here while the W stream is still in flight.
#pragma unroll
    for (int it = 0; it < 8; ++it) {
      const int idx = it * 256 + t;
      const int r = idx >> 5, i4 = idx & 31;
      const int off = chunk_idx(r >> 4, i4 >> 3, (i4 >> 1) & 3, r & 15) * 8 + (i4 & 1) * 4;
      uint2 ha;
      ha.x = pack_bf16(xv[it].x, xv[it].y);
      ha.y = pack_bf16(xv[it].z, xv[it].w);
      *(uint2*)&sA[off] = ha;
    }
    // Stage W second (drains the W stream as it arrives).
#pragma unroll
    for (int it = 0; it < 8; ++it) {
      const int idx = it * 256 + t;
      const int r = idx >> 5, i4 = idx & 31;
      const int off = chunk_idx(r >> 4, i4 >> 3, (i4 >> 1) & 3, r & 15) * 8 + (i4 & 1) * 4;
      uint2 hb;
      hb.x = pack_bf16(wv[it].x, wv[it].y);
      hb.y = pack_bf16(wv[it].z, wv[it].w);
      *(uint2*)&sB[off] = hb;
    }

    // prefetch next j's globals into registers (overlaps MFMA below); X first.
    if (jj + 1 < j1) {
      const int l = lmax - (jj + 1);
      const int k = (p & 1) + 2 * (jj + 1);
      const int xbase = l * 32;
      const int wbase = (k * L_ + l) * 4096 + oh * 2048;
#pragma unroll
      for (int it = 0; it < 8; ++it) {
        const int idx = it * 256 + t;
        xv[it] = X4[((idx >> 5) << 14) + xbase + (idx & 31)];
      }
#pragma unroll
      for (int it = 0; it < 8; ++it) {
        const int idx = it * 256 + t;
        wv[it] = __builtin_nontemporal_load(&W4[wbase + idx]);
      }
    }

    __syncthreads();  // LDS writes visible

    // wave computes 32x32 = 2x2 tiles of 16x16, K = 128 in 4 steps of 32
#pragma unroll
    for (int ks = 0; ks < 4; ++ks) {
      const v8s a0 = *(const v8s*)&sA[chunk_idx(wb * 2 + 0, ks, q, rm) * 8];
      const v8s a1 = *(const v8s*)&sA[chunk_idx(wb * 2 + 1, ks, q, rm) * 8];
      const v8s b0 = *(const v8s*)&sB[chunk_idx(wq * 2 + 0, ks, q, rm) * 8];
      const v8s b1 = *(const v8s*)&sB[chunk_idx(wq * 2 + 1, ks, q, rm) * 8];
      acc[0][0] = __builtin_amdgcn_mfma_f32_16x16x32_bf16(a0, b0, acc[0][0], 0, 0, 0);
      acc[0][1] = __builtin_amdgcn_mfma_f32_16x16x32_bf16(a0, b1, acc[0][1], 0, 0, 0);
      acc[1][0] = __builtin_amdgcn_mfma_f32_16x16x32_bf16(a1, b0, acc[1][0], 0, 0, 0);
      acc[1][1] = __builtin_amdgcn_mfma_f32_16x16x32_bf16(a1, b1, acc[1][1], 0, 0, 0);
    }
  }

  // epilogue: C/D layout col = lane&15, row = (lane>>4)*4 + reg
#pragma unroll
  for (int oo = 0; oo < 2; ++oo) {
    const int o = oh * 64 + wq * 32 + oo * 16 + rm;
    const float bv = bias[p * CO_ + o];
#pragma unroll
    for (int bb = 0; bb < 2; ++bb) {
#pragma unroll
      for (int rr = 0; rr < 4; ++rr) {
        const int b = wb * 32 + bb * 16 + q * 4 + rr;
        __builtin_nontemporal_store(acc[bb][oo][rr] + bv,
                                    &out[((size_t)b * P_ + p) * CO_ + o]);
      }
    }
  }
}

extern "C" void kernel_launch(void* const* d_in, const int* in_sizes, int n_in,
                              void* d_out, int out_size, void* d_ws, size_t ws_size,
                              hipStream_t stream) {
  const float* x    = (const float*)d_in[0];
  const float* w    = (const float*)d_in[1];
  const float* bias = (const float*)d_in[2];
  float* out        = (float*)d_out;
  hipLaunchKernelGGL(tdconv_mfma_kernel, dim3(P_ * 2), dim3(256), 0, stream,
                     x, w, bias, out);
}